// Round 11
// baseline (193.943 us; speedup 1.0000x reference)
//
#include <hip/hip_runtime.h>
#include <cmath>

#define SEQ    2048
#define DMODEL 1024
#define NHEADS 16
#define DK     64
#define MROWS  4096   // B*S
#define PITCH  72     // flash K/Q LDS pitch (bf16 elems)
#define VPITCH 68     // flash V^T permuted LDS pitch

typedef __bf16 bf16x8 __attribute__((ext_vector_type(8)));
typedef float  f32x4  __attribute__((ext_vector_type(4)));
typedef short  s16x4  __attribute__((ext_vector_type(4)));

__device__ __forceinline__ unsigned short f2bf(float f) {
    union { float f; unsigned u; } v; v.f = f;
    unsigned r = v.u + 0x7fffu + ((v.u >> 16) & 1u);   // RNE
    return (unsigned short)(r >> 16);
}

__device__ __forceinline__ void async16(const unsigned short* g, unsigned short* l) {
    __builtin_amdgcn_global_load_lds(
        (const __attribute__((address_space(1))) unsigned int*)(g),
        (__attribute__((address_space(3))) unsigned int*)(l),
        16, 0, 0);
}

// ---------------------------------------------------------------------------
// fp32 -> bf16 conversion of x, Wq|Wk|Wv (packed), Wo
// ---------------------------------------------------------------------------
__global__ __launch_bounds__(256)
void convert_kernel(const float* __restrict__ x,
                    const float* __restrict__ wq, const float* __restrict__ wk,
                    const float* __restrict__ wv, const float* __restrict__ wo,
                    unsigned short* __restrict__ xb,
                    unsigned short* __restrict__ wqkvb,
                    unsigned short* __restrict__ wob)
{
    const unsigned e = (blockIdx.x * 256u + threadIdx.x) * 8u;
    const float* src; unsigned short* dst; unsigned off;
    if      (e < 4194304u) { src = x;  dst = xb;             off = e;            }
    else if (e < 5242880u) { src = wq; dst = wqkvb;          off = e - 4194304u; }
    else if (e < 6291456u) { src = wk; dst = wqkvb+1048576u; off = e - 5242880u; }
    else if (e < 7340032u) { src = wv; dst = wqkvb+2097152u; off = e - 6291456u; }
    else                   { src = wo; dst = wob;            off = e - 7340032u; }
    float4 a = *(const float4*)(src + off);
    float4 b = *(const float4*)(src + off + 4);
    ushort4 u0, u1;
    u0.x=f2bf(a.x); u0.y=f2bf(a.y); u0.z=f2bf(a.z); u0.w=f2bf(a.w);
    u1.x=f2bf(b.x); u1.y=f2bf(b.y); u1.z=f2bf(b.z); u1.w=f2bf(b.w);
    *(ushort4*)(dst + off)     = u0;
    *(ushort4*)(dst + off + 4) = u1;
}

// ---------------------------------------------------------------------------
// bf16 MFMA GEMM: A[M][1024] @ B[NCOLS][1024]^T.  BK=64, coalesced async16
// staging (8 rows x 8 lanes per inst, XOR-8 slot swizzle; see R9), now with
// LDS DOUBLE-BUFFERING: one barrier per iter; next tile's async16 issued
// right after the barrier, so the compiler's vmcnt(0)-before-barrier waits
// on loads that had a full iteration (~600 cyc of MFMA+LDS) in flight.
// MODE 0: fp32 row-major out (O-proj).
// MODE 1: QKV split: cols <2048 -> RoPE + bf16 QK buf [4096][2048];
//         cols >=2048 -> V written transposed [b][d][s] (contiguous per lane).
// ---------------------------------------------------------------------------
template<int TM, int NCOLS, int MODE>
__global__ __launch_bounds__(256)
void gemm_mfma_bt(const unsigned short* __restrict__ A,
                  const unsigned short* __restrict__ B,
                  void* __restrict__ Yqk,
                  unsigned short* __restrict__ Yvt)
{
    constexpr int AINST = TM / 32;
    constexpr int MT    = (TM == 128) ? 4 : 2;
    constexpr int ASZ   = TM * 64;
    constexpr int BSZ   = 128 * 64;

    __shared__ unsigned short As[2 * ASZ];
    __shared__ unsigned short Bs[2 * BSZ];

    const int t    = threadIdx.x;
    const int w    = t >> 6;
    const int lane = t & 63;
    const int lq   = lane >> 4;
    const int ln   = lane & 15;
    const int m0   = blockIdx.y * TM;
    const int n0   = blockIdx.x * 128;

    const int mrow0 = (TM == 128) ? (w >> 1) * 64 : (w & 1) * 32;
    const int ncol0 = (TM == 128) ? (w & 1) * 64  : (w >> 1) * 64;

    const int srow  = w*8 + (lane >> 3);
    const int gslot = (lane & 7) ^ (lane >> 3);

    const unsigned short* gA[AINST]; unsigned short* lA[AINST];
    #pragma unroll
    for (int i = 0; i < AINST; ++i) {
        gA[i] = A + (size_t)(m0 + i*32 + srow) * 1024 + gslot*8;
        lA[i] = As + (i*32 + w*8) * 64;
    }
    const unsigned short* gB[4]; unsigned short* lB[4];
    #pragma unroll
    for (int i = 0; i < 4; ++i) {
        gB[i] = B + (size_t)(n0 + i*32 + srow) * 1024 + gslot*8;
        lB[i] = Bs + (i*32 + w*8) * 64;
    }

    f32x4 acc[MT][4];
    #pragma unroll
    for (int mt = 0; mt < MT; ++mt)
        #pragma unroll
        for (int nt = 0; nt < 4; ++nt)
            #pragma unroll
            for (int r = 0; r < 4; ++r) acc[mt][nt][r] = 0.0f;

    const int fsw = (ln & 7);

    // prologue: tile 0 -> buffer 0
    #pragma unroll
    for (int i = 0; i < AINST; ++i) async16(gA[i], lA[i]);
    #pragma unroll
    for (int i = 0; i < 4;     ++i) async16(gB[i], lB[i]);

    for (int it = 0; it < 16; ++it) {
        const int cur = (it & 1);
        __syncthreads();                 // drains cur's loads (1 iter old); prev reads done
        if (it < 15) {                   // issue next tile into other buffer
            const int nk  = (it + 1) * 64;
            const int nof = (cur ^ 1);
            #pragma unroll
            for (int i = 0; i < AINST; ++i) async16(gA[i] + nk, lA[i] + nof*ASZ);
            #pragma unroll
            for (int i = 0; i < 4;     ++i) async16(gB[i] + nk, lB[i] + nof*BSZ);
        }
        const unsigned short* Ac = As + cur*ASZ;
        const unsigned short* Bc = Bs + cur*BSZ;
        #pragma unroll
        for (int kh = 0; kh < 2; ++kh) {
            const int g  = kh*4 + lq;
            const int ps = (g ^ fsw) * 8;
            bf16x8 af[MT], bf[4];
            #pragma unroll
            for (int mt = 0; mt < MT; ++mt)
                af[mt] = *(const bf16x8*)&Ac[(mrow0 + mt*16 + ln)*64 + ps];
            #pragma unroll
            for (int nt = 0; nt < 4; ++nt)
                bf[nt] = *(const bf16x8*)&Bc[(ncol0 + nt*16 + ln)*64 + ps];
            #pragma unroll
            for (int mt = 0; mt < MT; ++mt)
                #pragma unroll
                for (int nt = 0; nt < 4; ++nt)
                    acc[mt][nt] = __builtin_amdgcn_mfma_f32_16x16x32_bf16(
                                      af[mt], bf[nt], acc[mt][nt], 0, 0, 0);
        }
    }

    if (MODE == 0) {
        float* Yf = (float*)Yqk;
        #pragma unroll
        for (int nt = 0; nt < 4; ++nt) {
            const int col = n0 + ncol0 + nt*16 + ln;
            #pragma unroll
            for (int mt = 0; mt < MT; ++mt) {
                const int row0 = m0 + mrow0 + mt*16 + lq*4;
                #pragma unroll
                for (int r = 0; r < 4; ++r)
                    Yf[(size_t)(row0 + r) * NCOLS + col] = acc[mt][nt][r];
            }
        }
    } else if (n0 < 2048) {
        // QK region: RoPE, bf16 row-major LD 2048
        unsigned short* Yb = (unsigned short*)Yqk;
        const float LOG_T = 9.210340371976184f / 32.0f;
        #pragma unroll
        for (int nt = 0; nt < 4; ++nt) {
            const int col = n0 + ncol0 + nt*16 + ln;
            const float fr = __expf(-(float)((col & 63) >> 1) * LOG_T);
            #pragma unroll
            for (int mt = 0; mt < MT; ++mt) {
                const int row0 = m0 + mrow0 + mt*16 + lq*4;
                #pragma unroll
                for (int r = 0; r < 4; ++r) {
                    const float v = acc[mt][nt][r];
                    float sn, cs;
                    __sincosf((float)((row0 + r) & (SEQ - 1)) * fr, &sn, &cs);
                    const float p = __shfl_xor(v, 1);
                    const float outv = ((ln & 1) == 0) ? (v*cs - p*sn) : (p*sn + v*cs);
                    Yb[(size_t)(row0 + r) * 2048 + col] = f2bf(outv);
                }
            }
        }
    } else {
        // V region: write transposed [b][d][s]; lane's 4 rows contiguous in s
        #pragma unroll
        for (int nt = 0; nt < 4; ++nt) {
            const int d = (n0 - 2048) + ncol0 + nt*16 + ln;
            #pragma unroll
            for (int mt = 0; mt < MT; ++mt) {
                const int row0 = m0 + mrow0 + mt*16 + lq*4;
                const int b = row0 >> 11;
                const int s = row0 & 2047;
                ushort4 o;
                o.x = f2bf(acc[mt][nt][0]); o.y = f2bf(acc[mt][nt][1]);
                o.z = f2bf(acc[mt][nt][2]); o.w = f2bf(acc[mt][nt][3]);
                *(ushort4*)&Yvt[((size_t)b*1024 + d) * 2048 + s] = o;
            }
        }
    }
}

// ---------------------------------------------------------------------------
// MFMA flash attention, transposed-P, pair-balanced, max-free softmax.
// V^T LDS tile now stored PERMUTED: Vt[d*68 + lq*16 + ks*4 + r] holds
// V^T[d][ks*16 + lq*4 + r], so each lane's PV A-frags for all 4 ks come from
// TWO ds_read_b128 per dt (was 4 conflicted ds_read_b64). Staging is 4
// lane-ordered ds_write_b64 per thread. All patterns bank-balanced.
// ---------------------------------------------------------------------------
__global__ __launch_bounds__(256)
void flash_mfma_kernel(const unsigned short* __restrict__ QK,
                       const unsigned short* __restrict__ Vtg,
                       unsigned short* __restrict__ Ob)
{
    __shared__ unsigned short Kt[64 * PITCH];    // Q stage / K tile / O transpose
    __shared__ unsigned short Vt[64 * VPITCH];   // V^T tile, permuted layout

    const int t    = threadIdx.x;
    const int w    = t >> 6;
    const int lane = t & 63;
    const int lq   = lane >> 4;
    const int ln   = lane & 15;
    const int bh   = blockIdx.x;
    const int iy   = blockIdx.y;                // pair index 0..15
    const int b    = bh >> 4;
    const int h    = bh & 15;

    const unsigned short* Qg = QK + h*DK;                        // LD 2048
    const unsigned short* Kg = QK + 1024 + h*DK;                 // LD 2048
    const unsigned short* Vg = Vtg + ((size_t)b*1024 + h*DK) * 2048;  // [d][s]

    const int sr = t >> 2;            // staging row 0..63
    const int sc = (t & 3) * 16;      // staging col 0,16,32,48
    const int ks = t & 3;             // this thread's key-subtile for V staging

    const float SCALE2 = 0.125f * 1.4426950408889634f;   // 1/sqrt(dk) * log2e

    for (int ph = 0; ph < 2; ++ph) {
        const int qb = ph ? iy : 31 - iy;       // heavy tile first

        __syncthreads();                        // Kt free (prev phase done)
        {   // stage Q tile -> Kt
            const unsigned short* qp = Qg + (size_t)(b*SEQ + qb*64 + sr) * 2048 + sc;
            *(float4*)&Kt[sr*PITCH + sc]     = *(const float4*)qp;
            *(float4*)&Kt[sr*PITCH + sc + 8] = *(const float4*)(qp + 8);
        }
        float4 kA, kB, vA, vB;
        {   // preload K/V^T tile 0 into registers
            const unsigned short* kp = Kg + (size_t)(b*SEQ + sr) * 2048 + sc;
            kA = *(const float4*)kp;  kB = *(const float4*)(kp + 8);
            const unsigned short* vp = Vg + (size_t)sr * 2048 + sc;   // d=sr
            vA = *(const float4*)vp;  vB = *(const float4*)(vp + 8);
        }
        __syncthreads();
        const bf16x8 qf0 = *(const bf16x8*)&Kt[(w*16 + ln)*PITCH + lq*8];
        const bf16x8 qf1 = *(const bf16x8*)&Kt[(w*16 + ln)*PITCH + 32 + lq*8];

        f32x4 oacc[4];
        #pragma unroll
        for (int dt = 0; dt < 4; ++dt)
            #pragma unroll
            for (int r = 0; r < 4; ++r) oacc[dt][r] = 0.0f;
        float l_r = 0.0f;
        const int qg = qb*64 + w*16 + ln;

        for (int kt = 0; kt <= qb; ++kt) {
            __syncthreads();                    // qf read / prev tile consumed
            *(float4*)&Kt[sr*PITCH + sc]     = kA;
            *(float4*)&Kt[sr*PITCH + sc + 8] = kB;
            {   // permuted V^T staging: 4 ds_write_b64
                const ushort4* va4 = (const ushort4*)&vA;
                const ushort4* vb4 = (const ushort4*)&vB;
                unsigned short* vbase = &Vt[sr*VPITCH + ks*4];
                *(ushort4*)(vbase +  0) = va4[0];
                *(ushort4*)(vbase + 16) = va4[1];
                *(ushort4*)(vbase + 32) = vb4[0];
                *(ushort4*)(vbase + 48) = vb4[1];
            }
            __syncthreads();                    // tile visible

            if (kt < qb) {                      // prefetch next tile
                const unsigned short* kp = Kg + (size_t)(b*SEQ + (kt+1)*64 + sr) * 2048 + sc;
                kA = *(const float4*)kp;  kB = *(const float4*)(kp + 8);
                const unsigned short* vp = Vg + (size_t)sr * 2048 + (kt+1)*64 + sc;
                vA = *(const float4*)vp;  vB = *(const float4*)(vp + 8);
            }

            // --- S^T = K Q^T
            f32x4 sacc[4];
            #pragma unroll
            for (int nt = 0; nt < 4; ++nt) {
                #pragma unroll
                for (int r = 0; r < 4; ++r) sacc[nt][r] = 0.0f;
                bf16x8 kf0 = *(const bf16x8*)&Kt[(nt*16 + ln)*PITCH + lq*8];
                bf16x8 kf1 = *(const bf16x8*)&Kt[(nt*16 + ln)*PITCH + 32 + lq*8];
                sacc[nt] = __builtin_amdgcn_mfma_f32_16x16x32_bf16(kf0, qf0, sacc[nt], 0, 0, 0);
                sacc[nt] = __builtin_amdgcn_mfma_f32_16x16x32_bf16(kf1, qf1, sacc[nt], 0, 0, 0);
            }

            // --- max-free softmax: p = exp2(min(s*scale, 50)); no cross-lane
            float p[16];
            if (kt == qb) {                     // diag tile: causal mask
                #pragma unroll
                for (int nt = 0; nt < 4; ++nt)
                    #pragma unroll
                    for (int r = 0; r < 4; ++r) {
                        float s = fminf(sacc[nt][r] * SCALE2, 50.0f);
                        if (kt*64 + nt*16 + lq*4 + r > qg) s = -INFINITY;
                        p[nt*4 + r] = __builtin_amdgcn_exp2f(s);
                    }
            } else {
                #pragma unroll
                for (int i = 0; i < 16; ++i) {
                    const int nt = i >> 2, r = i & 3;
                    p[i] = __builtin_amdgcn_exp2f(fminf(sacc[nt][r] * SCALE2, 50.0f));
                }
            }
            float sum = 0.0f;
            #pragma unroll
            for (int i = 0; i < 16; ++i) sum += p[i];
            l_r += sum;

            // --- pack P^T (round-half-up via +0x8000, pack with v_perm)
            s16x4 pf[4];
            #pragma unroll
            for (int kk = 0; kk < 4; ++kk) {
                union { float f; unsigned u; } c0, c1, c2, c3;
                c0.f = p[kk*4+0]; c1.f = p[kk*4+1]; c2.f = p[kk*4+2]; c3.f = p[kk*4+3];
                unsigned lo = __builtin_amdgcn_perm(c1.u + 0x8000u, c0.u + 0x8000u, 0x07060302u);
                unsigned hi = __builtin_amdgcn_perm(c3.u + 0x8000u, c2.u + 0x8000u, 0x07060302u);
                union { unsigned u2[2]; s16x4 v; } pk;
                pk.u2[0] = lo; pk.u2[1] = hi;
                pf[kk] = pk.v;
            }

            // --- O^T += V^T P^T  (V-frags: 2 b128 per dt, permuted layout)
            #pragma unroll
            for (int dt = 0; dt < 4; ++dt) {
                union { bf16x8 v8; s16x4 h[2]; } u01, u23;
                u01.v8 = *(const bf16x8*)&Vt[(dt*16 + ln)*VPITCH + lq*16];
                u23.v8 = *(const bf16x8*)&Vt[(dt*16 + ln)*VPITCH + lq*16 + 8];
                oacc[dt] = __builtin_amdgcn_mfma_f32_16x16x16bf16_1k(u01.h[0], pf[0], oacc[dt], 0, 0, 0);
                oacc[dt] = __builtin_amdgcn_mfma_f32_16x16x16bf16_1k(u01.h[1], pf[1], oacc[dt], 0, 0, 0);
                oacc[dt] = __builtin_amdgcn_mfma_f32_16x16x16bf16_1k(u23.h[0], pf[2], oacc[dt], 0, 0, 0);
                oacc[dt] = __builtin_amdgcn_mfma_f32_16x16x16bf16_1k(u23.h[1], pf[3], oacc[dt], 0, 0, 0);
            }
        }

        // --- epilogue: reduce l across quads, normalize, transpose via Kt, store
        l_r += __shfl_xor(l_r, 16);
        l_r += __shfl_xor(l_r, 32);
        const float linv = 1.0f / l_r;
        __syncthreads();                        // last tile reads done
        #pragma unroll
        for (int dt = 0; dt < 4; ++dt)
            #pragma unroll
            for (int r = 0; r < 4; ++r)
                Kt[(w*16 + ln)*PITCH + dt*16 + lq*4 + r] = f2bf(oacc[dt][r] * linv);
        __syncthreads();
        {
            unsigned short* op = Ob + (size_t)(b*SEQ + qb*64 + sr) * DMODEL + h*DK + sc;
            *(float4*)(op)     = *(const float4*)&Kt[sr*PITCH + sc];
            *(float4*)(op + 8) = *(const float4*)&Kt[sr*PITCH + sc + 8];
        }
    }
}

// ---------------------------------------------------------------------------
extern "C" void kernel_launch(void* const* d_in, const int* in_sizes, int n_in,
                              void* d_out, int out_size, void* d_ws, size_t ws_size,
                              hipStream_t stream)
{
    const float* x  = (const float*)d_in[0];
    const float* Wq = (const float*)d_in[1];
    const float* Wk = (const float*)d_in[2];
    const float* Wv = (const float*)d_in[3];
    const float* Wo = (const float*)d_in[4];
    float* out = (float*)d_out;

    unsigned short* xb    = (unsigned short*)d_ws;   //  4M elems
    unsigned short* wqkvb = xb + 4194304;            //  3M
    unsigned short* wob   = wqkvb + 3145728;         //  1M
    unsigned short* qk    = wob + 1048576;           //  8M  [4096][2048]
    unsigned short* vt    = qk + 8388608;            //  4M  [2][1024][2048]
    unsigned short* ob    = vt + 4194304;            //  4M  [4096][1024]
    // total 24M elems = 48 MB

    convert_kernel<<<4096, 256, 0, stream>>>(x, Wq, Wk, Wv, Wo, xb, wqkvb, wob);

    gemm_mfma_bt<128, 2048, 1><<<dim3(24, 32), 256, 0, stream>>>(xb, wqkvb, qk, vt);

    flash_mfma_kernel<<<dim3(32, 16), 256, 0, stream>>>(qk, vt, ob);

    gemm_mfma_bt<64, 1024, 0><<<dim3(8, 64), 256, 0, stream>>>(ob, wob, out, nullptr);
}

// Round 12
// 177.165 us; speedup vs baseline: 1.0947x; 1.0947x over previous
//
#include <hip/hip_runtime.h>
#include <cmath>

#define SEQ    2048
#define DMODEL 1024
#define NHEADS 16
#define DK     64
#define MROWS  4096   // B*S
#define PITCH  72     // flash K/Q LDS pitch (bf16 elems)
#define VPITCH 68     // flash V^T permuted LDS pitch

typedef __bf16 bf16x8 __attribute__((ext_vector_type(8)));
typedef float  f32x4  __attribute__((ext_vector_type(4)));
typedef short  s16x4  __attribute__((ext_vector_type(4)));

__device__ __forceinline__ unsigned short f2bf(float f) {
    union { float f; unsigned u; } v; v.f = f;
    unsigned r = v.u + 0x7fffu + ((v.u >> 16) & 1u);   // RNE
    return (unsigned short)(r >> 16);
}

__device__ __forceinline__ void async16(const unsigned short* g, unsigned short* l) {
    __builtin_amdgcn_global_load_lds(
        (const __attribute__((address_space(1))) unsigned int*)(g),
        (__attribute__((address_space(3))) unsigned int*)(l),
        16, 0, 0);
}

// ---------------------------------------------------------------------------
// fp32 -> bf16 conversion of x, Wq|Wk|Wv (packed), Wo
// ---------------------------------------------------------------------------
__global__ __launch_bounds__(256)
void convert_kernel(const float* __restrict__ x,
                    const float* __restrict__ wq, const float* __restrict__ wk,
                    const float* __restrict__ wv, const float* __restrict__ wo,
                    unsigned short* __restrict__ xb,
                    unsigned short* __restrict__ wqkvb,
                    unsigned short* __restrict__ wob)
{
    const unsigned e = (blockIdx.x * 256u + threadIdx.x) * 8u;
    const float* src; unsigned short* dst; unsigned off;
    if      (e < 4194304u) { src = x;  dst = xb;             off = e;            }
    else if (e < 5242880u) { src = wq; dst = wqkvb;          off = e - 4194304u; }
    else if (e < 6291456u) { src = wk; dst = wqkvb+1048576u; off = e - 5242880u; }
    else if (e < 7340032u) { src = wv; dst = wqkvb+2097152u; off = e - 6291456u; }
    else                   { src = wo; dst = wob;            off = e - 7340032u; }
    float4 a = *(const float4*)(src + off);
    float4 b = *(const float4*)(src + off + 4);
    ushort4 u0, u1;
    u0.x=f2bf(a.x); u0.y=f2bf(a.y); u0.z=f2bf(a.z); u0.w=f2bf(a.w);
    u1.x=f2bf(b.x); u1.y=f2bf(b.y); u1.z=f2bf(b.z); u1.w=f2bf(b.w);
    *(ushort4*)(dst + off)     = u0;
    *(ushort4*)(dst + off + 4) = u1;
}

// ---------------------------------------------------------------------------
// bf16 MFMA GEMM: A[M][1024] @ B[NCOLS][1024]^T.  BK=64, single-buffered
// (R10 config — measured best; dbuf regressed via occupancy, see R11 PM).
// Coalesced async16 staging (8 rows x 8 lanes per inst, XOR-8 slot swizzle).
// MODE 0: fp32 row-major out (O-proj).
// MODE 1: QKV split: cols <2048 -> RoPE + bf16 QK buf [4096][2048];
//         cols >=2048 -> V written transposed [b][d][s] (contiguous per lane).
// ---------------------------------------------------------------------------
template<int TM, int NCOLS, int MODE>
__global__ __launch_bounds__(256)
void gemm_mfma_bt(const unsigned short* __restrict__ A,
                  const unsigned short* __restrict__ B,
                  void* __restrict__ Yqk,
                  unsigned short* __restrict__ Yvt)
{
    constexpr int AINST = TM / 32;
    constexpr int MT    = (TM == 128) ? 4 : 2;

    __shared__ unsigned short As[TM * 64];
    __shared__ unsigned short Bs[128 * 64];

    const int t    = threadIdx.x;
    const int w    = t >> 6;
    const int lane = t & 63;
    const int lq   = lane >> 4;
    const int ln   = lane & 15;
    const int m0   = blockIdx.y * TM;
    const int n0   = blockIdx.x * 128;

    const int mrow0 = (TM == 128) ? (w >> 1) * 64 : (w & 1) * 32;
    const int ncol0 = (TM == 128) ? (w & 1) * 64  : (w >> 1) * 64;

    const int srow  = w*8 + (lane >> 3);
    const int gslot = (lane & 7) ^ (lane >> 3);

    const unsigned short* gA[AINST]; unsigned short* lA[AINST];
    #pragma unroll
    for (int i = 0; i < AINST; ++i) {
        gA[i] = A + (size_t)(m0 + i*32 + srow) * 1024 + gslot*8;
        lA[i] = As + (i*32 + w*8) * 64;
    }
    const unsigned short* gB[4]; unsigned short* lB[4];
    #pragma unroll
    for (int i = 0; i < 4; ++i) {
        gB[i] = B + (size_t)(n0 + i*32 + srow) * 1024 + gslot*8;
        lB[i] = Bs + (i*32 + w*8) * 64;
    }

    f32x4 acc[MT][4];
    #pragma unroll
    for (int mt = 0; mt < MT; ++mt)
        #pragma unroll
        for (int nt = 0; nt < 4; ++nt)
            #pragma unroll
            for (int r = 0; r < 4; ++r) acc[mt][nt][r] = 0.0f;

    const int fsw = (ln & 7);

    for (int k0 = 0; k0 < 1024; k0 += 64) {
        __syncthreads();
        #pragma unroll
        for (int i = 0; i < AINST; ++i) async16(gA[i] + k0, lA[i]);
        #pragma unroll
        for (int i = 0; i < 4;     ++i) async16(gB[i] + k0, lB[i]);
        __syncthreads();
        #pragma unroll
        for (int kh = 0; kh < 2; ++kh) {
            const int g  = kh*4 + lq;
            const int ps = (g ^ fsw) * 8;
            bf16x8 af[MT], bf[4];
            #pragma unroll
            for (int mt = 0; mt < MT; ++mt)
                af[mt] = *(const bf16x8*)&As[(mrow0 + mt*16 + ln)*64 + ps];
            #pragma unroll
            for (int nt = 0; nt < 4; ++nt)
                bf[nt] = *(const bf16x8*)&Bs[(ncol0 + nt*16 + ln)*64 + ps];
            #pragma unroll
            for (int mt = 0; mt < MT; ++mt)
                #pragma unroll
                for (int nt = 0; nt < 4; ++nt)
                    acc[mt][nt] = __builtin_amdgcn_mfma_f32_16x16x32_bf16(
                                      af[mt], bf[nt], acc[mt][nt], 0, 0, 0);
        }
    }

    if (MODE == 0) {
        float* Yf = (float*)Yqk;
        #pragma unroll
        for (int nt = 0; nt < 4; ++nt) {
            const int col = n0 + ncol0 + nt*16 + ln;
            #pragma unroll
            for (int mt = 0; mt < MT; ++mt) {
                const int row0 = m0 + mrow0 + mt*16 + lq*4;
                #pragma unroll
                for (int r = 0; r < 4; ++r)
                    Yf[(size_t)(row0 + r) * NCOLS + col] = acc[mt][nt][r];
            }
        }
    } else if (n0 < 2048) {
        // QK region: RoPE, bf16 row-major LD 2048
        unsigned short* Yb = (unsigned short*)Yqk;
        const float LOG_T = 9.210340371976184f / 32.0f;
        #pragma unroll
        for (int nt = 0; nt < 4; ++nt) {
            const int col = n0 + ncol0 + nt*16 + ln;
            const float fr = __expf(-(float)((col & 63) >> 1) * LOG_T);
            #pragma unroll
            for (int mt = 0; mt < MT; ++mt) {
                const int row0 = m0 + mrow0 + mt*16 + lq*4;
                #pragma unroll
                for (int r = 0; r < 4; ++r) {
                    const float v = acc[mt][nt][r];
                    float sn, cs;
                    __sincosf((float)((row0 + r) & (SEQ - 1)) * fr, &sn, &cs);
                    const float p = __shfl_xor(v, 1);
                    const float outv = ((ln & 1) == 0) ? (v*cs - p*sn) : (p*sn + v*cs);
                    Yb[(size_t)(row0 + r) * 2048 + col] = f2bf(outv);
                }
            }
        }
    } else {
        // V region: write transposed [b][d][s]; lane's 4 rows contiguous in s
        #pragma unroll
        for (int nt = 0; nt < 4; ++nt) {
            const int d = (n0 - 2048) + ncol0 + nt*16 + ln;
            #pragma unroll
            for (int mt = 0; mt < MT; ++mt) {
                const int row0 = m0 + mrow0 + mt*16 + lq*4;
                const int b = row0 >> 11;
                const int s = row0 & 2047;
                ushort4 o;
                o.x = f2bf(acc[mt][nt][0]); o.y = f2bf(acc[mt][nt][1]);
                o.z = f2bf(acc[mt][nt][2]); o.w = f2bf(acc[mt][nt][3]);
                *(ushort4*)&Yvt[((size_t)b*1024 + d) * 2048 + s] = o;
            }
        }
    }
}

// ---------------------------------------------------------------------------
// MFMA flash attention, transposed-P, max-free softmax, permuted-V LDS.
// SINGLE q-tile per block (grid 32 bh x 32 qb = 1024 blocks ~ 4/CU): the lean
// kernel (17.9 KB LDS, 60 VGPR) admits 8 blocks/CU, so co-residency now beats
// pair-balancing (R11 PM: occupancy > source pipelining on this structure).
// Heavy tiles (qb=31) dispatch first; light tiles backfill the tail.
// ---------------------------------------------------------------------------
__global__ __launch_bounds__(256)
void flash_mfma_kernel(const unsigned short* __restrict__ QK,
                       const unsigned short* __restrict__ Vtg,
                       unsigned short* __restrict__ Ob)
{
    __shared__ unsigned short Kt[64 * PITCH];    // Q stage / K tile / O transpose
    __shared__ unsigned short Vt[64 * VPITCH];   // V^T tile, permuted layout

    const int t    = threadIdx.x;
    const int w    = t >> 6;
    const int lane = t & 63;
    const int lq   = lane >> 4;
    const int ln   = lane & 15;
    const int bh   = blockIdx.x;
    const int qb   = 31 - (int)blockIdx.y;      // heavy first
    const int b    = bh >> 4;
    const int h    = bh & 15;

    const unsigned short* Qg = QK + h*DK;                        // LD 2048
    const unsigned short* Kg = QK + 1024 + h*DK;                 // LD 2048
    const unsigned short* Vg = Vtg + ((size_t)b*1024 + h*DK) * 2048;  // [d][s]

    const int sr = t >> 2;            // staging row 0..63
    const int sc = (t & 3) * 16;      // staging col 0,16,32,48
    const int ks = t & 3;             // this thread's key-subtile for V staging

    const float SCALE2 = 0.125f * 1.4426950408889634f;   // 1/sqrt(dk) * log2e

    {   // stage Q tile -> Kt
        const unsigned short* qp = Qg + (size_t)(b*SEQ + qb*64 + sr) * 2048 + sc;
        *(float4*)&Kt[sr*PITCH + sc]     = *(const float4*)qp;
        *(float4*)&Kt[sr*PITCH + sc + 8] = *(const float4*)(qp + 8);
    }
    float4 kA, kB, vA, vB;
    {   // preload K/V^T tile 0 into registers
        const unsigned short* kp = Kg + (size_t)(b*SEQ + sr) * 2048 + sc;
        kA = *(const float4*)kp;  kB = *(const float4*)(kp + 8);
        const unsigned short* vp = Vg + (size_t)sr * 2048 + sc;   // d=sr
        vA = *(const float4*)vp;  vB = *(const float4*)(vp + 8);
    }
    __syncthreads();
    const bf16x8 qf0 = *(const bf16x8*)&Kt[(w*16 + ln)*PITCH + lq*8];
    const bf16x8 qf1 = *(const bf16x8*)&Kt[(w*16 + ln)*PITCH + 32 + lq*8];

    f32x4 oacc[4];
    #pragma unroll
    for (int dt = 0; dt < 4; ++dt)
        #pragma unroll
        for (int r = 0; r < 4; ++r) oacc[dt][r] = 0.0f;
    float l_r = 0.0f;
    const int qg = qb*64 + w*16 + ln;

    for (int kt = 0; kt <= qb; ++kt) {
        __syncthreads();                    // qf read / prev tile consumed
        *(float4*)&Kt[sr*PITCH + sc]     = kA;
        *(float4*)&Kt[sr*PITCH + sc + 8] = kB;
        {   // permuted V^T staging: 4 ds_write_b64
            const ushort4* va4 = (const ushort4*)&vA;
            const ushort4* vb4 = (const ushort4*)&vB;
            unsigned short* vbase = &Vt[sr*VPITCH + ks*4];
            *(ushort4*)(vbase +  0) = va4[0];
            *(ushort4*)(vbase + 16) = va4[1];
            *(ushort4*)(vbase + 32) = vb4[0];
            *(ushort4*)(vbase + 48) = vb4[1];
        }
        __syncthreads();                    // tile visible

        if (kt < qb) {                      // prefetch next tile
            const unsigned short* kp = Kg + (size_t)(b*SEQ + (kt+1)*64 + sr) * 2048 + sc;
            kA = *(const float4*)kp;  kB = *(const float4*)(kp + 8);
            const unsigned short* vp = Vg + (size_t)sr * 2048 + (kt+1)*64 + sc;
            vA = *(const float4*)vp;  vB = *(const float4*)(vp + 8);
        }

        // --- S^T = K Q^T
        f32x4 sacc[4];
        #pragma unroll
        for (int nt = 0; nt < 4; ++nt) {
            #pragma unroll
            for (int r = 0; r < 4; ++r) sacc[nt][r] = 0.0f;
            bf16x8 kf0 = *(const bf16x8*)&Kt[(nt*16 + ln)*PITCH + lq*8];
            bf16x8 kf1 = *(const bf16x8*)&Kt[(nt*16 + ln)*PITCH + 32 + lq*8];
            sacc[nt] = __builtin_amdgcn_mfma_f32_16x16x32_bf16(kf0, qf0, sacc[nt], 0, 0, 0);
            sacc[nt] = __builtin_amdgcn_mfma_f32_16x16x32_bf16(kf1, qf1, sacc[nt], 0, 0, 0);
        }

        // --- max-free softmax: p = exp2(min(s*scale, 50)); no cross-lane
        float p[16];
        if (kt == qb) {                     // diag tile: causal mask
            #pragma unroll
            for (int nt = 0; nt < 4; ++nt)
                #pragma unroll
                for (int r = 0; r < 4; ++r) {
                    float s = fminf(sacc[nt][r] * SCALE2, 50.0f);
                    if (kt*64 + nt*16 + lq*4 + r > qg) s = -INFINITY;
                    p[nt*4 + r] = __builtin_amdgcn_exp2f(s);
                }
        } else {
            #pragma unroll
            for (int i = 0; i < 16; ++i) {
                const int nt = i >> 2, r = i & 3;
                p[i] = __builtin_amdgcn_exp2f(fminf(sacc[nt][r] * SCALE2, 50.0f));
            }
        }
        float sum = 0.0f;
        #pragma unroll
        for (int i = 0; i < 16; ++i) sum += p[i];
        l_r += sum;

        // --- pack P^T (round-half-up via +0x8000, pack with v_perm)
        s16x4 pf[4];
        #pragma unroll
        for (int kk = 0; kk < 4; ++kk) {
            union { float f; unsigned u; } c0, c1, c2, c3;
            c0.f = p[kk*4+0]; c1.f = p[kk*4+1]; c2.f = p[kk*4+2]; c3.f = p[kk*4+3];
            unsigned lo = __builtin_amdgcn_perm(c1.u + 0x8000u, c0.u + 0x8000u, 0x07060302u);
            unsigned hi = __builtin_amdgcn_perm(c3.u + 0x8000u, c2.u + 0x8000u, 0x07060302u);
            union { unsigned u2[2]; s16x4 v; } pk;
            pk.u2[0] = lo; pk.u2[1] = hi;
            pf[kk] = pk.v;
        }

        // --- O^T += V^T P^T  (V-frags: 2 b128 per dt, permuted layout)
        #pragma unroll
        for (int dt = 0; dt < 4; ++dt) {
            union { bf16x8 v8; s16x4 h[2]; } u01, u23;
            u01.v8 = *(const bf16x8*)&Vt[(dt*16 + ln)*VPITCH + lq*16];
            u23.v8 = *(const bf16x8*)&Vt[(dt*16 + ln)*VPITCH + lq*16 + 8];
            oacc[dt] = __builtin_amdgcn_mfma_f32_16x16x16bf16_1k(u01.h[0], pf[0], oacc[dt], 0, 0, 0);
            oacc[dt] = __builtin_amdgcn_mfma_f32_16x16x16bf16_1k(u01.h[1], pf[1], oacc[dt], 0, 0, 0);
            oacc[dt] = __builtin_amdgcn_mfma_f32_16x16x16bf16_1k(u23.h[0], pf[2], oacc[dt], 0, 0, 0);
            oacc[dt] = __builtin_amdgcn_mfma_f32_16x16x16bf16_1k(u23.h[1], pf[3], oacc[dt], 0, 0, 0);
        }
    }

    // --- epilogue: reduce l across quads, normalize, transpose via Kt, store
    l_r += __shfl_xor(l_r, 16);
    l_r += __shfl_xor(l_r, 32);
    const float linv = 1.0f / l_r;
    __syncthreads();                        // last tile reads done
    #pragma unroll
    for (int dt = 0; dt < 4; ++dt)
        #pragma unroll
        for (int r = 0; r < 4; ++r)
            Kt[(w*16 + ln)*PITCH + dt*16 + lq*4 + r] = f2bf(oacc[dt][r] * linv);
    __syncthreads();
    {
        unsigned short* op = Ob + (size_t)(b*SEQ + qb*64 + sr) * DMODEL + h*DK + sc;
        *(float4*)(op)     = *(const float4*)&Kt[sr*PITCH + sc];
        *(float4*)(op + 8) = *(const float4*)&Kt[sr*PITCH + sc + 8];
    }
}

// ---------------------------------------------------------------------------
extern "C" void kernel_launch(void* const* d_in, const int* in_sizes, int n_in,
                              void* d_out, int out_size, void* d_ws, size_t ws_size,
                              hipStream_t stream)
{
    const float* x  = (const float*)d_in[0];
    const float* Wq = (const float*)d_in[1];
    const float* Wk = (const float*)d_in[2];
    const float* Wv = (const float*)d_in[3];
    const float* Wo = (const float*)d_in[4];
    float* out = (float*)d_out;

    unsigned short* xb    = (unsigned short*)d_ws;   //  4M elems
    unsigned short* wqkvb = xb + 4194304;            //  3M
    unsigned short* wob   = wqkvb + 3145728;         //  1M
    unsigned short* qk    = wob + 1048576;           //  8M  [4096][2048]
    unsigned short* vt    = qk + 8388608;            //  4M  [2][1024][2048]
    unsigned short* ob    = vt + 4194304;            //  4M  [4096][1024]
    // total 24M elems = 48 MB

    convert_kernel<<<4096, 256, 0, stream>>>(x, Wq, Wk, Wv, Wo, xb, wqkvb, wob);

    gemm_mfma_bt<128, 2048, 1><<<dim3(24, 32), 256, 0, stream>>>(xb, wqkvb, qk, vt);

    flash_mfma_kernel<<<dim3(32, 32), 256, 0, stream>>>(qk, vt, ob);

    gemm_mfma_bt<64, 1024, 0><<<dim3(8, 64), 256, 0, stream>>>(ob, wob, out, nullptr);
}

// Round 13
// 168.092 us; speedup vs baseline: 1.1538x; 1.0540x over previous
//
#include <hip/hip_runtime.h>
#include <cmath>

#define SEQ    2048
#define DMODEL 1024
#define NHEADS 16
#define DK     64
#define MROWS  4096   // B*S
#define PITCH  72     // flash K/Q LDS pitch (bf16 elems)
#define VPITCH 68     // flash V^T permuted LDS pitch

typedef __bf16 bf16x8 __attribute__((ext_vector_type(8)));
typedef float  f32x4  __attribute__((ext_vector_type(4)));
typedef short  s16x4  __attribute__((ext_vector_type(4)));

__device__ __forceinline__ unsigned short f2bf(float f) {
    union { float f; unsigned u; } v; v.f = f;
    unsigned r = v.u + 0x7fffu + ((v.u >> 16) & 1u);   // RNE
    return (unsigned short)(r >> 16);
}

__device__ __forceinline__ void async16(const unsigned short* g, unsigned short* l) {
    __builtin_amdgcn_global_load_lds(
        (const __attribute__((address_space(1))) unsigned int*)(g),
        (__attribute__((address_space(3))) unsigned int*)(l),
        16, 0, 0);
}

// ---------------------------------------------------------------------------
// fp32 -> bf16 conversion of x, Wq|Wk|Wv (packed), Wo
// ---------------------------------------------------------------------------
__global__ __launch_bounds__(256)
void convert_kernel(const float* __restrict__ x,
                    const float* __restrict__ wq, const float* __restrict__ wk,
                    const float* __restrict__ wv, const float* __restrict__ wo,
                    unsigned short* __restrict__ xb,
                    unsigned short* __restrict__ wqkvb,
                    unsigned short* __restrict__ wob)
{
    const unsigned e = (blockIdx.x * 256u + threadIdx.x) * 8u;
    const float* src; unsigned short* dst; unsigned off;
    if      (e < 4194304u) { src = x;  dst = xb;             off = e;            }
    else if (e < 5242880u) { src = wq; dst = wqkvb;          off = e - 4194304u; }
    else if (e < 6291456u) { src = wk; dst = wqkvb+1048576u; off = e - 5242880u; }
    else if (e < 7340032u) { src = wv; dst = wqkvb+2097152u; off = e - 6291456u; }
    else                   { src = wo; dst = wob;            off = e - 7340032u; }
    float4 a = *(const float4*)(src + off);
    float4 b = *(const float4*)(src + off + 4);
    ushort4 u0, u1;
    u0.x=f2bf(a.x); u0.y=f2bf(a.y); u0.z=f2bf(a.z); u0.w=f2bf(a.w);
    u1.x=f2bf(b.x); u1.y=f2bf(b.y); u1.z=f2bf(b.z); u1.w=f2bf(b.w);
    *(ushort4*)(dst + off)     = u0;
    *(ushort4*)(dst + off + 4) = u1;
}

// ---------------------------------------------------------------------------
// bf16 MFMA GEMM: Y = A[M][1024] @ B[NCOLS][1024]^T.  TM=64 fixed, TN
// templated. BK=64 single-buffered (R11 PM: dbuf loses via occupancy).
// OCCUPANCY PUSH (R12 PM: QKV at 3 waves/SIMD, all pipes <35% busy, the
// vmcnt drain per K-step is the stall): smaller tiles -> more blocks/CU.
// QKV: TM=64 x TN=128, grid (24,64)=1536 blocks -> 6 blocks/CU;
// O-proj: 64x64, grid (16,64)=1024 -> 4/CU. launch_bounds(256,6) caps VGPR
// at 85 so 6 waves/SIMD fit. Coalesced async16 staging + XOR-8 slot swizzle.
// MODE 0: fp32 row-major out (O-proj).
// MODE 1: QKV split: cols <2048 -> RoPE + bf16 QK buf [4096][2048];
//         cols >=2048 -> V transposed [b][d][s] (contiguous per lane).
// ---------------------------------------------------------------------------
template<int TN, int NCOLS, int MODE>
__global__ __launch_bounds__(256, 6)
void gemm_mfma_bt(const unsigned short* __restrict__ A,
                  const unsigned short* __restrict__ B,
                  void* __restrict__ Yqk,
                  unsigned short* __restrict__ Yvt)
{
    constexpr int BINST = TN / 32;      // B async16 insts per thread
    constexpr int NT    = TN / 32;      // 16-col frags per wave

    __shared__ unsigned short As[64 * 64];
    __shared__ unsigned short Bs[TN * 64];

    const int t    = threadIdx.x;
    const int w    = t >> 6;
    const int lane = t & 63;
    const int lq   = lane >> 4;
    const int ln   = lane & 15;
    const int m0   = blockIdx.y * 64;
    const int n0   = blockIdx.x * TN;

    const int mrow0 = (w & 1) * 32;            // wave tile: 32 x (TN/2)
    const int ncol0 = (w >> 1) * (TN / 2);

    const int srow  = w*8 + (lane >> 3);
    const int gslot = (lane & 7) ^ (lane >> 3);

    const unsigned short* gA[2]; unsigned short* lA[2];
    #pragma unroll
    for (int i = 0; i < 2; ++i) {
        gA[i] = A + (size_t)(m0 + i*32 + srow) * 1024 + gslot*8;
        lA[i] = As + (i*32 + w*8) * 64;
    }
    const unsigned short* gB[BINST]; unsigned short* lB[BINST];
    #pragma unroll
    for (int i = 0; i < BINST; ++i) {
        gB[i] = B + (size_t)(n0 + i*32 + srow) * 1024 + gslot*8;
        lB[i] = Bs + (i*32 + w*8) * 64;
    }

    f32x4 acc[2][NT];
    #pragma unroll
    for (int mt = 0; mt < 2; ++mt)
        #pragma unroll
        for (int nt = 0; nt < NT; ++nt)
            #pragma unroll
            for (int r = 0; r < 4; ++r) acc[mt][nt][r] = 0.0f;

    const int fsw = (ln & 7);

    for (int k0 = 0; k0 < 1024; k0 += 64) {
        __syncthreads();
        #pragma unroll
        for (int i = 0; i < 2;     ++i) async16(gA[i] + k0, lA[i]);
        #pragma unroll
        for (int i = 0; i < BINST; ++i) async16(gB[i] + k0, lB[i]);
        __syncthreads();
        #pragma unroll
        for (int kh = 0; kh < 2; ++kh) {
            const int g  = kh*4 + lq;
            const int ps = (g ^ fsw) * 8;
            bf16x8 af[2], bf[NT];
            #pragma unroll
            for (int mt = 0; mt < 2; ++mt)
                af[mt] = *(const bf16x8*)&As[(mrow0 + mt*16 + ln)*64 + ps];
            #pragma unroll
            for (int nt = 0; nt < NT; ++nt)
                bf[nt] = *(const bf16x8*)&Bs[(ncol0 + nt*16 + ln)*64 + ps];
            #pragma unroll
            for (int mt = 0; mt < 2; ++mt)
                #pragma unroll
                for (int nt = 0; nt < NT; ++nt)
                    acc[mt][nt] = __builtin_amdgcn_mfma_f32_16x16x32_bf16(
                                      af[mt], bf[nt], acc[mt][nt], 0, 0, 0);
        }
    }

    if (MODE == 0) {
        float* Yf = (float*)Yqk;
        #pragma unroll
        for (int nt = 0; nt < NT; ++nt) {
            const int col = n0 + ncol0 + nt*16 + ln;
            #pragma unroll
            for (int mt = 0; mt < 2; ++mt) {
                const int row0 = m0 + mrow0 + mt*16 + lq*4;
                #pragma unroll
                for (int r = 0; r < 4; ++r)
                    Yf[(size_t)(row0 + r) * NCOLS + col] = acc[mt][nt][r];
            }
        }
    } else if (n0 < 2048) {
        // QK region: RoPE, bf16 row-major LD 2048
        unsigned short* Yb = (unsigned short*)Yqk;
        const float LOG_T = 9.210340371976184f / 32.0f;
        #pragma unroll
        for (int nt = 0; nt < NT; ++nt) {
            const int col = n0 + ncol0 + nt*16 + ln;
            const float fr = __expf(-(float)((col & 63) >> 1) * LOG_T);
            #pragma unroll
            for (int mt = 0; mt < 2; ++mt) {
                const int row0 = m0 + mrow0 + mt*16 + lq*4;
                #pragma unroll
                for (int r = 0; r < 4; ++r) {
                    const float v = acc[mt][nt][r];
                    float sn, cs;
                    __sincosf((float)((row0 + r) & (SEQ - 1)) * fr, &sn, &cs);
                    const float p = __shfl_xor(v, 1);
                    const float outv = ((ln & 1) == 0) ? (v*cs - p*sn) : (p*sn + v*cs);
                    Yb[(size_t)(row0 + r) * 2048 + col] = f2bf(outv);
                }
            }
        }
    } else {
        // V region: write transposed [b][d][s]; lane's 4 rows contiguous in s
        #pragma unroll
        for (int nt = 0; nt < NT; ++nt) {
            const int d = (n0 - 2048) + ncol0 + nt*16 + ln;
            #pragma unroll
            for (int mt = 0; mt < 2; ++mt) {
                const int row0 = m0 + mrow0 + mt*16 + lq*4;
                const int b = row0 >> 11;
                const int s = row0 & 2047;
                ushort4 o;
                o.x = f2bf(acc[mt][nt][0]); o.y = f2bf(acc[mt][nt][1]);
                o.z = f2bf(acc[mt][nt][2]); o.w = f2bf(acc[mt][nt][3]);
                *(ushort4*)&Yvt[((size_t)b*1024 + d) * 2048 + s] = o;
            }
        }
    }
}

// ---------------------------------------------------------------------------
// MFMA flash attention, transposed-P, max-free softmax, permuted-V LDS.
// Single q-tile per block, grid 32 bh x 32 qb; heavy tiles first.
// (unchanged from round 12)
// ---------------------------------------------------------------------------
__global__ __launch_bounds__(256)
void flash_mfma_kernel(const unsigned short* __restrict__ QK,
                       const unsigned short* __restrict__ Vtg,
                       unsigned short* __restrict__ Ob)
{
    __shared__ unsigned short Kt[64 * PITCH];    // Q stage / K tile / O transpose
    __shared__ unsigned short Vt[64 * VPITCH];   // V^T tile, permuted layout

    const int t    = threadIdx.x;
    const int w    = t >> 6;
    const int lane = t & 63;
    const int lq   = lane >> 4;
    const int ln   = lane & 15;
    const int bh   = blockIdx.x;
    const int qb   = 31 - (int)blockIdx.y;      // heavy first
    const int b    = bh >> 4;
    const int h    = bh & 15;

    const unsigned short* Qg = QK + h*DK;                        // LD 2048
    const unsigned short* Kg = QK + 1024 + h*DK;                 // LD 2048
    const unsigned short* Vg = Vtg + ((size_t)b*1024 + h*DK) * 2048;  // [d][s]

    const int sr = t >> 2;            // staging row 0..63
    const int sc = (t & 3) * 16;      // staging col 0,16,32,48
    const int ks = t & 3;             // this thread's key-subtile for V staging

    const float SCALE2 = 0.125f * 1.4426950408889634f;   // 1/sqrt(dk) * log2e

    {   // stage Q tile -> Kt
        const unsigned short* qp = Qg + (size_t)(b*SEQ + qb*64 + sr) * 2048 + sc;
        *(float4*)&Kt[sr*PITCH + sc]     = *(const float4*)qp;
        *(float4*)&Kt[sr*PITCH + sc + 8] = *(const float4*)(qp + 8);
    }
    float4 kA, kB, vA, vB;
    {   // preload K/V^T tile 0 into registers
        const unsigned short* kp = Kg + (size_t)(b*SEQ + sr) * 2048 + sc;
        kA = *(const float4*)kp;  kB = *(const float4*)(kp + 8);
        const unsigned short* vp = Vg + (size_t)sr * 2048 + sc;   // d=sr
        vA = *(const float4*)vp;  vB = *(const float4*)(vp + 8);
    }
    __syncthreads();
    const bf16x8 qf0 = *(const bf16x8*)&Kt[(w*16 + ln)*PITCH + lq*8];
    const bf16x8 qf1 = *(const bf16x8*)&Kt[(w*16 + ln)*PITCH + 32 + lq*8];

    f32x4 oacc[4];
    #pragma unroll
    for (int dt = 0; dt < 4; ++dt)
        #pragma unroll
        for (int r = 0; r < 4; ++r) oacc[dt][r] = 0.0f;
    float l_r = 0.0f;
    const int qg = qb*64 + w*16 + ln;

    for (int kt = 0; kt <= qb; ++kt) {
        __syncthreads();                    // qf read / prev tile consumed
        *(float4*)&Kt[sr*PITCH + sc]     = kA;
        *(float4*)&Kt[sr*PITCH + sc + 8] = kB;
        {   // permuted V^T staging: 4 ds_write_b64
            const ushort4* va4 = (const ushort4*)&vA;
            const ushort4* vb4 = (const ushort4*)&vB;
            unsigned short* vbase = &Vt[sr*VPITCH + ks*4];
            *(ushort4*)(vbase +  0) = va4[0];
            *(ushort4*)(vbase + 16) = va4[1];
            *(ushort4*)(vbase + 32) = vb4[0];
            *(ushort4*)(vbase + 48) = vb4[1];
        }
        __syncthreads();                    // tile visible

        if (kt < qb) {                      // prefetch next tile
            const unsigned short* kp = Kg + (size_t)(b*SEQ + (kt+1)*64 + sr) * 2048 + sc;
            kA = *(const float4*)kp;  kB = *(const float4*)(kp + 8);
            const unsigned short* vp = Vg + (size_t)sr * 2048 + (kt+1)*64 + sc;
            vA = *(const float4*)vp;  vB = *(const float4*)(vp + 8);
        }

        // --- S^T = K Q^T
        f32x4 sacc[4];
        #pragma unroll
        for (int nt = 0; nt < 4; ++nt) {
            #pragma unroll
            for (int r = 0; r < 4; ++r) sacc[nt][r] = 0.0f;
            bf16x8 kf0 = *(const bf16x8*)&Kt[(nt*16 + ln)*PITCH + lq*8];
            bf16x8 kf1 = *(const bf16x8*)&Kt[(nt*16 + ln)*PITCH + 32 + lq*8];
            sacc[nt] = __builtin_amdgcn_mfma_f32_16x16x32_bf16(kf0, qf0, sacc[nt], 0, 0, 0);
            sacc[nt] = __builtin_amdgcn_mfma_f32_16x16x32_bf16(kf1, qf1, sacc[nt], 0, 0, 0);
        }

        // --- max-free softmax: p = exp2(min(s*scale, 50)); no cross-lane
        float p[16];
        if (kt == qb) {                     // diag tile: causal mask
            #pragma unroll
            for (int nt = 0; nt < 4; ++nt)
                #pragma unroll
                for (int r = 0; r < 4; ++r) {
                    float s = fminf(sacc[nt][r] * SCALE2, 50.0f);
                    if (kt*64 + nt*16 + lq*4 + r > qg) s = -INFINITY;
                    p[nt*4 + r] = __builtin_amdgcn_exp2f(s);
                }
        } else {
            #pragma unroll
            for (int i = 0; i < 16; ++i) {
                const int nt = i >> 2, r = i & 3;
                p[i] = __builtin_amdgcn_exp2f(fminf(sacc[nt][r] * SCALE2, 50.0f));
            }
        }
        float sum = 0.0f;
        #pragma unroll
        for (int i = 0; i < 16; ++i) sum += p[i];
        l_r += sum;

        // --- pack P^T (round-half-up via +0x8000, pack with v_perm)
        s16x4 pf[4];
        #pragma unroll
        for (int kk = 0; kk < 4; ++kk) {
            union { float f; unsigned u; } c0, c1, c2, c3;
            c0.f = p[kk*4+0]; c1.f = p[kk*4+1]; c2.f = p[kk*4+2]; c3.f = p[kk*4+3];
            unsigned lo = __builtin_amdgcn_perm(c1.u + 0x8000u, c0.u + 0x8000u, 0x07060302u);
            unsigned hi = __builtin_amdgcn_perm(c3.u + 0x8000u, c2.u + 0x8000u, 0x07060302u);
            union { unsigned u2[2]; s16x4 v; } pk;
            pk.u2[0] = lo; pk.u2[1] = hi;
            pf[kk] = pk.v;
        }

        // --- O^T += V^T P^T  (V-frags: 2 b128 per dt, permuted layout)
        #pragma unroll
        for (int dt = 0; dt < 4; ++dt) {
            union { bf16x8 v8; s16x4 h[2]; } u01, u23;
            u01.v8 = *(const bf16x8*)&Vt[(dt*16 + ln)*VPITCH + lq*16];
            u23.v8 = *(const bf16x8*)&Vt[(dt*16 + ln)*VPITCH + lq*16 + 8];
            oacc[dt] = __builtin_amdgcn_mfma_f32_16x16x16bf16_1k(u01.h[0], pf[0], oacc[dt], 0, 0, 0);
            oacc[dt] = __builtin_amdgcn_mfma_f32_16x16x16bf16_1k(u01.h[1], pf[1], oacc[dt], 0, 0, 0);
            oacc[dt] = __builtin_amdgcn_mfma_f32_16x16x16bf16_1k(u23.h[0], pf[2], oacc[dt], 0, 0, 0);
            oacc[dt] = __builtin_amdgcn_mfma_f32_16x16x16bf16_1k(u23.h[1], pf[3], oacc[dt], 0, 0, 0);
        }
    }

    // --- epilogue: reduce l across quads, normalize, transpose via Kt, store
    l_r += __shfl_xor(l_r, 16);
    l_r += __shfl_xor(l_r, 32);
    const float linv = 1.0f / l_r;
    __syncthreads();                        // last tile reads done
    #pragma unroll
    for (int dt = 0; dt < 4; ++dt)
        #pragma unroll
        for (int r = 0; r < 4; ++r)
            Kt[(w*16 + ln)*PITCH + dt*16 + lq*4 + r] = f2bf(oacc[dt][r] * linv);
    __syncthreads();
    {
        unsigned short* op = Ob + (size_t)(b*SEQ + qb*64 + sr) * DMODEL + h*DK + sc;
        *(float4*)(op)     = *(const float4*)&Kt[sr*PITCH + sc];
        *(float4*)(op + 8) = *(const float4*)&Kt[sr*PITCH + sc + 8];
    }
}

// ---------------------------------------------------------------------------
extern "C" void kernel_launch(void* const* d_in, const int* in_sizes, int n_in,
                              void* d_out, int out_size, void* d_ws, size_t ws_size,
                              hipStream_t stream)
{
    const float* x  = (const float*)d_in[0];
    const float* Wq = (const float*)d_in[1];
    const float* Wk = (const float*)d_in[2];
    const float* Wv = (const float*)d_in[3];
    const float* Wo = (const float*)d_in[4];
    float* out = (float*)d_out;

    unsigned short* xb    = (unsigned short*)d_ws;   //  4M elems
    unsigned short* wqkvb = xb + 4194304;            //  3M
    unsigned short* wob   = wqkvb + 3145728;         //  1M
    unsigned short* qk    = wob + 1048576;           //  8M  [4096][2048]
    unsigned short* vt    = qk + 8388608;            //  4M  [2][1024][2048]
    unsigned short* ob    = vt + 4194304;            //  4M  [4096][1024]
    // total 24M elems = 48 MB

    convert_kernel<<<4096, 256, 0, stream>>>(x, Wq, Wk, Wv, Wo, xb, wqkvb, wob);

    // QKV: 64x128 tiles, 1536 blocks (~6/CU)
    gemm_mfma_bt<128, 2048, 1><<<dim3(24, 64), 256, 0, stream>>>(xb, wqkvb, qk, vt);

    flash_mfma_kernel<<<dim3(32, 32), 256, 0, stream>>>(qk, vt, ob);

    // O-proj: 64x64 tiles, 1024 blocks (4/CU)
    gemm_mfma_bt<64, 1024, 0><<<dim3(16, 64), 256, 0, stream>>>(ob, wob, out, nullptr);
}